// Round 4
// baseline (858.112 us; speedup 1.0000x reference)
//
#include <hip/hip_runtime.h>
#include <hip/hip_bf16.h>

// RNN: emb[x] -> xw GEMM -> 256 sequential tanh steps -> fused FC.
// All matmuls in f16 MFMA (16x16x32) with f32 accumulate.
// B=64, T=256, H=E=512, O=4.
//
// R4: k2 at 1024 thr (4 waves/SIMD for latency hiding), areg 11 kc +
// fragS 4 kc + 1 kc L2-reload; FC fused into k2 (k3 deleted); k1 gets
// double-buffered staging (1 barrier/iter) + LDS-transpose coalesced stores.

typedef _Float16 f16;
typedef _Float16 f16x4 __attribute__((ext_vector_type(4)));
typedef _Float16 f16x8 __attribute__((ext_vector_type(8)));
typedef float    f32x4 __attribute__((ext_vector_type(4)));

// d_ws layout (bytes)
#define XWB_OFF   0u
#define XWB_BYTES (64u*256u*512u*2u)            // 16 MB: xw + b_ih + b_hh, f16 [B*T][H]
#define AWHH_OFF  (XWB_OFF + XWB_BYTES)         // 512 KB: W_hh A-operand fragments
#define BWIH_OFF  (AWHH_OFF + 512u*1024u)       // 512 KB: W_ih B-operand fragments

// ---------------------------------------------------------------------------
// K0: pack W_hh (A-op layout) and W_ih (B-op layout) into fragment-linear
// f16: frag (kc, tile) at ((kc*32 + tile)*64 + lane)*8 f16.
// ---------------------------------------------------------------------------
__global__ __launch_bounds__(64) void k0_prep(const float* __restrict__ Whh,
                                              const float* __restrict__ Wih,
                                              f16* __restrict__ awhh,
                                              f16* __restrict__ bwih) {
    int id   = blockIdx.x;           // 0..1023
    int lane = threadIdx.x;          // 0..63
    bool is_ih = id >= 512;
    int lid = is_ih ? (id - 512) : id;       // = kc*32 + tile
    const float* src = is_ih ? Wih : Whh;
    f16* dst = is_ih ? bwih : awhh;
    int tile = lid & 31;
    int kc   = lid >> 5;
    int row  = tile * 16 + (lane & 15);
    int col0 = kc * 32 + (lane >> 4) * 8;
    const float* p = src + (size_t)row * 512 + col0;
    float4 v0 = *(const float4*)(p);
    float4 v1 = *(const float4*)(p + 4);
    f16x8 o;
    o[0] = (f16)v0.x; o[1] = (f16)v0.y; o[2] = (f16)v0.z; o[3] = (f16)v0.w;
    o[4] = (f16)v1.x; o[5] = (f16)v1.y; o[6] = (f16)v1.z; o[7] = (f16)v1.w;
    *(f16x8*)(dst + (size_t)lid * 512 + lane * 8) = o;
}

// ---------------------------------------------------------------------------
// K1: xwb[m][n] = sum_k emb[x[m]][k] * W_ih[n][k] + b_ih[n] + b_hh[n], f16.
// Double-buffered LDS staging (1 barrier/iter, next-next chunk's loads in
// flight across the barrier); epilogue transposes through LDS so global
// stores are 8 B/lane coalesced (R3 scattered 2-B stores).
// ---------------------------------------------------------------------------
__global__ __launch_bounds__(256) void k1_xw(const int* __restrict__ x,
                                             const float* __restrict__ emb,
                                             const float* __restrict__ bih,
                                             const float* __restrict__ bhh,
                                             const f16* __restrict__ bwih,
                                             f16* __restrict__ xwb) {
    __shared__ f16 Bs[2][16384];     // 64 KB: double-buffered k-chunk of B frags
    int tid  = threadIdx.x;
    int wave = tid >> 6, lane = tid & 63;
    int quad = lane >> 4, l15 = lane & 15;
    int mrow0 = blockIdx.x * 64 + wave * 16;

    int arow_idx = x[mrow0 + l15];                  // gathered embedding row
    const float* arow = emb + (size_t)arow_idx * 512;

    f32x4 acc[32];
#pragma unroll
    for (int nt = 0; nt < 32; ++nt) acc[nt] = (f32x4){0.f, 0.f, 0.f, 0.f};

    // prologue: stage kc=0, preload kc=1 into regs
    float4 L[8];
    {
        const float4* s4 = (const float4*)bwih;
#pragma unroll
        for (int q = 0; q < 8; ++q) L[q] = s4[q * 256 + tid];
#pragma unroll
        for (int q = 0; q < 8; ++q) ((float4*)Bs[0])[q * 256 + tid] = L[q];
        const float4* s4b = (const float4*)(bwih + 16384);
#pragma unroll
        for (int q = 0; q < 8; ++q) L[q] = s4b[q * 256 + tid];
    }
    __syncthreads();

    for (int kc = 0; kc < 16; ++kc) {
        int cur = kc & 1;

        float4 a0 = *(const float4*)(arow + kc * 32 + quad * 8);
        float4 a1 = *(const float4*)(arow + kc * 32 + quad * 8 + 4);
        f16x8 af;
        af[0] = (f16)a0.x; af[1] = (f16)a0.y; af[2] = (f16)a0.z; af[3] = (f16)a0.w;
        af[4] = (f16)a1.x; af[5] = (f16)a1.y; af[6] = (f16)a1.z; af[7] = (f16)a1.w;

#pragma unroll
        for (int nt = 0; nt < 32; ++nt) {
            f16x8 bf = *(const f16x8*)(&Bs[cur][0] + nt * 512 + lane * 8);
            acc[nt] = __builtin_amdgcn_mfma_f32_16x16x32_f16(af, bf, acc[nt], 0, 0, 0);
        }

        if (kc < 15) {   // store prefetched (kc+1) into the other buffer
#pragma unroll
            for (int q = 0; q < 8; ++q) ((float4*)Bs[cur ^ 1])[q * 256 + tid] = L[q];
        }
        __syncthreads();
        if (kc < 14) {   // issue loads for kc+2; drain covered by next MFMAs
            const float4* s4 = (const float4*)(bwih + (size_t)(kc + 2) * 16384);
#pragma unroll
            for (int q = 0; q < 8; ++q) L[q] = s4[q * 256 + tid];
        }
    }
    __syncthreads();   // Bs reads done everywhere; safe to reuse as scratch

    // Epilogue: transpose via per-wave LDS region, then coalesced stores.
    // trans row stride 264 f16 (528 B -> banks spread); region/wave 8448 B.
    f16* trans = (f16*)Bs + (size_t)wave * 4224;
#pragma unroll
    for (int half = 0; half < 2; ++half) {
#pragma unroll
        for (int nt2 = 0; nt2 < 16; ++nt2) {
            int nt = half * 16 + nt2;
            int n = nt * 16 + l15;
            float bias = bih[n] + bhh[n];
#pragma unroll
            for (int r = 0; r < 4; ++r)
                trans[(quad * 4 + r) * 264 + nt2 * 16 + l15] =
                    (f16)(acc[nt][r] + bias);
        }
        // wave-private region: compiler's lgkmcnt ordering suffices
#pragma unroll
        for (int row = 0; row < 16; ++row) {
            f16x4 v = *(const f16x4*)(trans + row * 264 + lane * 4);
            *(f16x4*)(xwb + (size_t)(mrow0 + row) * 512 + half * 256 + lane * 4) = v;
        }
        __syncthreads();  // all waves done with their region before half 1 reuse
    }
}

// ---------------------------------------------------------------------------
// K2: recurrence + fused FC. 16 WGs x 1024 thr (16 waves, 4/SIMD).
// WG owns batches wg*4..wg*4+3 (n-cols 0..3 of 16). Wave w owns m-tiles
// 2w, 2w+1. Per step: D[i][b] = sum_j W_hh[i][j]*h[b][j]; +xwb; tanh.
// W_hh residency: kc 0..10 VGPR (88 regs), kc 11..14 LDS fragS (128 KB),
// kc 15 reloaded from L2 each step (short live range, latency hidden).
// h double-buffered in LDS (stride 544). After t=255: FC in-kernel.
// ---------------------------------------------------------------------------
__global__ __launch_bounds__(1024, 4) void k2_rnn(const f16* __restrict__ awhh,
                                                  const f16* __restrict__ xwb,
                                                  const float* __restrict__ Wfc,
                                                  const float* __restrict__ bfc,
                                                  float* __restrict__ out) {
    extern __shared__ char smem[];
    f16* fragS = (f16*)smem;                               // 32*4*1024 = 131072 B
    f16* hbuf  = (f16*)(smem + 131072);                    // 2*4*544*2 = 8704 B

    int tid  = threadIdx.x;
    int wave = tid >> 6, lane = tid & 63;
    int quad = lane >> 4, n = lane & 15;
    int mtb  = wave * 2;
    int b    = blockIdx.x * 4 + n;               // valid only when n < 4

    // --- persistent A-frags, kc 0..10 ---
    f16x8 areg[2][11];
#pragma unroll
    for (int p = 0; p < 2; ++p)
#pragma unroll
        for (int kc = 0; kc < 11; ++kc)
            areg[p][kc] = *(const f16x8*)(awhh +
                ((size_t)(kc * 32 + mtb + p) * 64 + lane) * 8);

    // --- LDS-resident frags, kc 11..14 (per-wave-tile private region) ---
#pragma unroll
    for (int p = 0; p < 2; ++p)
#pragma unroll
        for (int j = 0; j < 4; ++j) {
            f16x8 v = *(const f16x8*)(awhh +
                ((size_t)((11 + j) * 32 + mtb + p) * 64 + lane) * 8);
            *(f16x8*)(fragS + (((mtb + p) * 4 + j) * 64 + lane) * 8) = v;
        }

    // --- zero h double-buffer ---
    {
        unsigned int* hz = (unsigned int*)hbuf;
        for (int i = tid; i < 2176; i += 1024) hz[i] = 0u;
    }
    __syncthreads();

    const f16* xwb_b = xwb + (size_t)b * 256 * 512;   // deref'd only when n<4

    for (int t = 0; t < 256; ++t) {
        const f16* hc = hbuf + (size_t)(t & 1) * 4 * 544;
        f16*       hn = hbuf + (size_t)((t + 1) & 1) * 4 * 544;

        // prefetch xw (h-independent; latency hidden by MFMA phase)
        f16x4 xw4[2];
        if (n < 4) {
#pragma unroll
            for (int p = 0; p < 2; ++p)
                xw4[p] = *(const f16x4*)(xwb_b + (size_t)t * 512 +
                                         (mtb + p) * 16 + quad * 4);
        }
        // kc 15 A-frags from L2 (t-invariant data, short-lived registers)
        f16x8 s15[2];
#pragma unroll
        for (int p = 0; p < 2; ++p)
            s15[p] = *(const f16x8*)(awhh +
                ((size_t)(15 * 32 + mtb + p) * 64 + lane) * 8);

        f32x4 acc[2];
#pragma unroll
        for (int p = 0; p < 2; ++p) acc[p] = (f32x4){0.f, 0.f, 0.f, 0.f};

#pragma unroll
        for (int kc = 0; kc < 11; ++kc) {
            f16x8 bf = {};
            if (n < 4)
                bf = *(const f16x8*)(hc + n * 544 + kc * 32 + quad * 8);
#pragma unroll
            for (int p = 0; p < 2; ++p)
                acc[p] = __builtin_amdgcn_mfma_f32_16x16x32_f16(
                    areg[p][kc], bf, acc[p], 0, 0, 0);
        }
#pragma unroll
        for (int j = 0; j < 4; ++j) {
            int kc = 11 + j;
            f16x8 bf = {};
            if (n < 4)
                bf = *(const f16x8*)(hc + n * 544 + kc * 32 + quad * 8);
#pragma unroll
            for (int p = 0; p < 2; ++p) {
                f16x8 af = *(const f16x8*)(fragS +
                    (((mtb + p) * 4 + j) * 64 + lane) * 8);
                acc[p] = __builtin_amdgcn_mfma_f32_16x16x32_f16(
                    af, bf, acc[p], 0, 0, 0);
            }
        }
        {
            f16x8 bf = {};
            if (n < 4)
                bf = *(const f16x8*)(hc + n * 544 + 15 * 32 + quad * 8);
#pragma unroll
            for (int p = 0; p < 2; ++p)
                acc[p] = __builtin_amdgcn_mfma_f32_16x16x32_f16(
                    s15[p], bf, acc[p], 0, 0, 0);
        }

        if (n < 4) {
#pragma unroll
            for (int p = 0; p < 2; ++p) {
                int i0 = (mtb + p) * 16 + quad * 4;
                f16x4 hv;
#pragma unroll
                for (int r = 0; r < 4; ++r) {
                    float z = acc[p][r] + (float)xw4[p][r];
                    float e = __expf(2.f * z);       // bounded: |z| small
                    hv[r] = (f16)((e - 1.f) / (e + 1.f));
                }
                *(f16x4*)(hn + n * 544 + i0) = hv;
            }
        }
        __syncthreads();   // h(t+1) fully written before next step reads it
    }

    // ---- fused FC: h_T is in hbuf (buffer 0). fragS is dead -> reduction LDS.
    float* red = (float*)smem;           // 512 floats
    if (tid < 512) {
        int bb = tid >> 7;               // 0..3
        int oo = (tid >> 5) & 3;         // 0..3
        int sg = tid & 31;               // 0..31 -> 16 i each
        const f16* hrow = hbuf + bb * 544;
        const float* wrow = Wfc + (size_t)oo * 512;
        float s = 0.f;
#pragma unroll
        for (int ii = 0; ii < 16; ++ii) {
            int i = sg * 16 + ii;
            s += (float)hrow[i] * wrow[i];
        }
        red[tid] = s;
    }
    __syncthreads();
    if (tid < 16) {
        int bb = tid >> 2, oo = tid & 3;
        float s = 0.f;
#pragma unroll
        for (int sg = 0; sg < 32; ++sg) s += red[(bb * 4 + oo) * 32 + sg];
        out[(blockIdx.x * 4 + bb) * 4 + oo] = s + bfc[oo];
    }
}

// ---------------------------------------------------------------------------
// K2 fallback (64-KB LDS): fragS 1 kc, kc 12..15 reloaded per step.
// Only used if the big-LDS attribute can't be set (not expected on MI355X).
// ---------------------------------------------------------------------------
__global__ __launch_bounds__(1024, 4) void k2_rnn_small(const f16* __restrict__ awhh,
                                                        const f16* __restrict__ xwb,
                                                        const float* __restrict__ Wfc,
                                                        const float* __restrict__ bfc,
                                                        float* __restrict__ out) {
    extern __shared__ char smem[];
    f16* fragS = (f16*)smem;                               // 32*1*1024 = 32768 B
    f16* hbuf  = (f16*)(smem + 32768);

    int tid  = threadIdx.x;
    int wave = tid >> 6, lane = tid & 63;
    int quad = lane >> 4, n = lane & 15;
    int mtb  = wave * 2;
    int b    = blockIdx.x * 4 + n;

    f16x8 areg[2][11];
#pragma unroll
    for (int p = 0; p < 2; ++p)
#pragma unroll
        for (int kc = 0; kc < 11; ++kc)
            areg[p][kc] = *(const f16x8*)(awhh +
                ((size_t)(kc * 32 + mtb + p) * 64 + lane) * 8);
#pragma unroll
    for (int p = 0; p < 2; ++p) {
        f16x8 v = *(const f16x8*)(awhh +
            ((size_t)(11 * 32 + mtb + p) * 64 + lane) * 8);
        *(f16x8*)(fragS + (((mtb + p)) * 64 + lane) * 8) = v;
    }
    {
        unsigned int* hz = (unsigned int*)hbuf;
        for (int i = tid; i < 2176; i += 1024) hz[i] = 0u;
    }
    __syncthreads();

    const f16* xwb_b = xwb + (size_t)b * 256 * 512;

    for (int t = 0; t < 256; ++t) {
        const f16* hc = hbuf + (size_t)(t & 1) * 4 * 544;
        f16*       hn = hbuf + (size_t)((t + 1) & 1) * 4 * 544;

        f16x4 xw4[2];
        if (n < 4) {
#pragma unroll
            for (int p = 0; p < 2; ++p)
                xw4[p] = *(const f16x4*)(xwb_b + (size_t)t * 512 +
                                         (mtb + p) * 16 + quad * 4);
        }
        f16x8 sst[4][2];
#pragma unroll
        for (int q = 0; q < 4; ++q)
#pragma unroll
            for (int p = 0; p < 2; ++p)
                sst[q][p] = *(const f16x8*)(awhh +
                    ((size_t)((12 + q) * 32 + mtb + p) * 64 + lane) * 8);

        f32x4 acc[2];
#pragma unroll
        for (int p = 0; p < 2; ++p) acc[p] = (f32x4){0.f, 0.f, 0.f, 0.f};

#pragma unroll
        for (int kc = 0; kc < 11; ++kc) {
            f16x8 bf = {};
            if (n < 4) bf = *(const f16x8*)(hc + n * 544 + kc * 32 + quad * 8);
#pragma unroll
            for (int p = 0; p < 2; ++p)
                acc[p] = __builtin_amdgcn_mfma_f32_16x16x32_f16(
                    areg[p][kc], bf, acc[p], 0, 0, 0);
        }
        {
            f16x8 bf = {};
            if (n < 4) bf = *(const f16x8*)(hc + n * 544 + 11 * 32 + quad * 8);
#pragma unroll
            for (int p = 0; p < 2; ++p) {
                f16x8 af = *(const f16x8*)(fragS + ((mtb + p) * 64 + lane) * 8);
                acc[p] = __builtin_amdgcn_mfma_f32_16x16x32_f16(af, bf, acc[p], 0, 0, 0);
            }
        }
#pragma unroll
        for (int q = 0; q < 4; ++q) {
            int kc = 12 + q;
            f16x8 bf = {};
            if (n < 4) bf = *(const f16x8*)(hc + n * 544 + kc * 32 + quad * 8);
#pragma unroll
            for (int p = 0; p < 2; ++p)
                acc[p] = __builtin_amdgcn_mfma_f32_16x16x32_f16(sst[q][p], bf, acc[p], 0, 0, 0);
        }

        if (n < 4) {
#pragma unroll
            for (int p = 0; p < 2; ++p) {
                int i0 = (mtb + p) * 16 + quad * 4;
                f16x4 hv;
#pragma unroll
                for (int r = 0; r < 4; ++r) {
                    float z = acc[p][r] + (float)xw4[p][r];
                    float e = __expf(2.f * z);
                    hv[r] = (f16)((e - 1.f) / (e + 1.f));
                }
                *(f16x4*)(hn + n * 544 + i0) = hv;
            }
        }
        __syncthreads();
    }

    float* red = (float*)smem;
    if (tid < 512) {
        int bb = tid >> 7, oo = (tid >> 5) & 3, sg = tid & 31;
        const f16* hrow = hbuf + bb * 544;
        const float* wrow = Wfc + (size_t)oo * 512;
        float s = 0.f;
#pragma unroll
        for (int ii = 0; ii < 16; ++ii) s += (float)hrow[sg * 16 + ii] * wrow[sg * 16 + ii];
        red[tid] = s;
    }
    __syncthreads();
    if (tid < 16) {
        int bb = tid >> 2, oo = tid & 3;
        float s = 0.f;
#pragma unroll
        for (int sg = 0; sg < 32; ++sg) s += red[(bb * 4 + oo) * 32 + sg];
        out[(blockIdx.x * 4 + bb) * 4 + oo] = s + bfc[oo];
    }
}

extern "C" void kernel_launch(void* const* d_in, const int* in_sizes, int n_in,
                              void* d_out, int out_size, void* d_ws, size_t ws_size,
                              hipStream_t stream) {
    const int*   x   = (const int*)d_in[0];
    const float* emb = (const float*)d_in[1];
    const float* Wih = (const float*)d_in[2];
    const float* Whh = (const float*)d_in[3];
    const float* bih = (const float*)d_in[4];
    const float* bhh = (const float*)d_in[5];
    const float* Wfc = (const float*)d_in[6];
    const float* bfc = (const float*)d_in[7];
    float* out = (float*)d_out;

    char* ws = (char*)d_ws;
    f16* xwb  = (f16*)(ws + XWB_OFF);
    f16* awhh = (f16*)(ws + AWHH_OFF);
    f16* bwih = (f16*)(ws + BWIH_OFF);

    hipLaunchKernelGGL(k0_prep, dim3(1024), dim3(64),  0, stream, Whh, Wih, awhh, bwih);
    hipLaunchKernelGGL(k1_xw,   dim3(256),  dim3(256), 0, stream, x, emb, bih, bhh, bwih, xwb);

    const int LDS_BIG   = 131072 + 8704;      // 139776
    const int LDS_SMALL = 32768 + 8704;       // 41472
    int dev = 0;
    (void)hipGetDevice(&dev);
    int maxlds = 0;
    (void)hipDeviceGetAttribute(&maxlds, hipDeviceAttributeMaxSharedMemoryPerBlock, dev);
    bool big = maxlds >= LDS_BIG;
    if (big)
        big = (hipFuncSetAttribute((const void*)&k2_rnn,
                                   hipFuncAttributeMaxDynamicSharedMemorySize,
                                   LDS_BIG) == hipSuccess);
    if (big) {
        hipLaunchKernelGGL(k2_rnn, dim3(16), dim3(1024), LDS_BIG, stream,
                           awhh, xwb, Wfc, bfc, out);
    } else {
        hipLaunchKernelGGL(k2_rnn_small, dim3(16), dim3(1024), LDS_SMALL, stream,
                           awhh, xwb, Wfc, bfc, out);
    }
}

// Round 5
// 730.456 us; speedup vs baseline: 1.1748x; 1.1748x over previous
//
#include <hip/hip_runtime.h>
#include <hip/hip_bf16.h>

// RNN: emb[x] -> xw GEMM -> 256 sequential tanh steps -> fused FC.
// All matmuls in f16 MFMA (16x16x32) with f32 accumulate.
// B=64, T=256, H=E=512, O=4.
//
// R5: back to R3's 512-thr shape (R4's 1024-thr + launch_bounds(.,4) capped
// regs at 64 and regressed). Overhead surgery on the step loop:
//  - h replicated across 8 LDS cols (stride 552 f16, 2-way alias = free):
//    no predication anywhere in the hot loop (all 64 lanes uniform).
//  - tanh quotient via __builtin_amdgcn_rcpf (was full-precision div seq).
//  - acc split into two 8-deep MFMA chains per tile (2x chain ILP).
//  - running xwb pointer (no per-step 64-bit addr recompute).

typedef _Float16 f16;
typedef _Float16 f16x4 __attribute__((ext_vector_type(4)));
typedef _Float16 f16x8 __attribute__((ext_vector_type(8)));
typedef float    f32x4 __attribute__((ext_vector_type(4)));

// d_ws layout (bytes)
#define XWB_OFF   0u
#define XWB_BYTES (64u*256u*512u*2u)            // 16 MB: xw + b_ih + b_hh, f16 [B*T][H]
#define AWHH_OFF  (XWB_OFF + XWB_BYTES)         // 512 KB: W_hh A-operand fragments
#define BWIH_OFF  (AWHH_OFF + 512u*1024u)       // 512 KB: W_ih B-operand fragments

#define HSTRIDE 552                              // f16 col stride: 1104 B -> 2-way banks

// ---------------------------------------------------------------------------
// K0: pack W_hh (A-op layout) and W_ih (B-op layout) into fragment-linear
// f16: frag (kc, tile) at ((kc*32 + tile)*64 + lane)*8 f16.
// ---------------------------------------------------------------------------
__global__ __launch_bounds__(64) void k0_prep(const float* __restrict__ Whh,
                                              const float* __restrict__ Wih,
                                              f16* __restrict__ awhh,
                                              f16* __restrict__ bwih) {
    int id   = blockIdx.x;           // 0..1023
    int lane = threadIdx.x;          // 0..63
    bool is_ih = id >= 512;
    int lid = is_ih ? (id - 512) : id;       // = kc*32 + tile
    const float* src = is_ih ? Wih : Whh;
    f16* dst = is_ih ? bwih : awhh;
    int tile = lid & 31;
    int kc   = lid >> 5;
    int row  = tile * 16 + (lane & 15);
    int col0 = kc * 32 + (lane >> 4) * 8;
    const float* p = src + (size_t)row * 512 + col0;
    float4 v0 = *(const float4*)(p);
    float4 v1 = *(const float4*)(p + 4);
    f16x8 o;
    o[0] = (f16)v0.x; o[1] = (f16)v0.y; o[2] = (f16)v0.z; o[3] = (f16)v0.w;
    o[4] = (f16)v1.x; o[5] = (f16)v1.y; o[6] = (f16)v1.z; o[7] = (f16)v1.w;
    *(f16x8*)(dst + (size_t)lid * 512 + lane * 8) = o;
}

// ---------------------------------------------------------------------------
// K1: xwb[m][n] = sum_k emb[x[m]][k] * W_ih[n][k] + b_ih[n] + b_hh[n], f16.
// Double-buffered LDS staging (1 barrier/iter); LDS-transpose epilogue for
// coalesced 8 B/lane stores.
// ---------------------------------------------------------------------------
__global__ __launch_bounds__(256) void k1_xw(const int* __restrict__ x,
                                             const float* __restrict__ emb,
                                             const float* __restrict__ bih,
                                             const float* __restrict__ bhh,
                                             const f16* __restrict__ bwih,
                                             f16* __restrict__ xwb) {
    __shared__ f16 Bs[2][16384];     // 64 KB: double-buffered k-chunk of B frags
    int tid  = threadIdx.x;
    int wave = tid >> 6, lane = tid & 63;
    int quad = lane >> 4, l15 = lane & 15;
    int mrow0 = blockIdx.x * 64 + wave * 16;

    int arow_idx = x[mrow0 + l15];                  // gathered embedding row
    const float* arow = emb + (size_t)arow_idx * 512;

    f32x4 acc[32];
#pragma unroll
    for (int nt = 0; nt < 32; ++nt) acc[nt] = (f32x4){0.f, 0.f, 0.f, 0.f};

    // prologue: stage kc=0, preload kc=1 into regs
    float4 L[8];
    {
        const float4* s4 = (const float4*)bwih;
#pragma unroll
        for (int q = 0; q < 8; ++q) L[q] = s4[q * 256 + tid];
#pragma unroll
        for (int q = 0; q < 8; ++q) ((float4*)Bs[0])[q * 256 + tid] = L[q];
        const float4* s4b = (const float4*)(bwih + 16384);
#pragma unroll
        for (int q = 0; q < 8; ++q) L[q] = s4b[q * 256 + tid];
    }
    __syncthreads();

    for (int kc = 0; kc < 16; ++kc) {
        int cur = kc & 1;

        float4 a0 = *(const float4*)(arow + kc * 32 + quad * 8);
        float4 a1 = *(const float4*)(arow + kc * 32 + quad * 8 + 4);
        f16x8 af;
        af[0] = (f16)a0.x; af[1] = (f16)a0.y; af[2] = (f16)a0.z; af[3] = (f16)a0.w;
        af[4] = (f16)a1.x; af[5] = (f16)a1.y; af[6] = (f16)a1.z; af[7] = (f16)a1.w;

#pragma unroll
        for (int nt = 0; nt < 32; ++nt) {
            f16x8 bf = *(const f16x8*)(&Bs[cur][0] + nt * 512 + lane * 8);
            acc[nt] = __builtin_amdgcn_mfma_f32_16x16x32_f16(af, bf, acc[nt], 0, 0, 0);
        }

        if (kc < 15) {   // store prefetched (kc+1) into the other buffer
#pragma unroll
            for (int q = 0; q < 8; ++q) ((float4*)Bs[cur ^ 1])[q * 256 + tid] = L[q];
        }
        __syncthreads();
        if (kc < 14) {   // issue loads for kc+2; drain covered by next MFMAs
            const float4* s4 = (const float4*)(bwih + (size_t)(kc + 2) * 16384);
#pragma unroll
            for (int q = 0; q < 8; ++q) L[q] = s4[q * 256 + tid];
        }
    }
    __syncthreads();   // Bs reads done everywhere; safe to reuse as scratch

    // Epilogue: transpose via per-wave LDS region, then coalesced stores.
    f16* trans = (f16*)Bs + (size_t)wave * 4224;
#pragma unroll
    for (int half = 0; half < 2; ++half) {
#pragma unroll
        for (int nt2 = 0; nt2 < 16; ++nt2) {
            int nt = half * 16 + nt2;
            int n = nt * 16 + l15;
            float bias = bih[n] + bhh[n];
#pragma unroll
            for (int r = 0; r < 4; ++r)
                trans[(quad * 4 + r) * 264 + nt2 * 16 + l15] =
                    (f16)(acc[nt][r] + bias);
        }
#pragma unroll
        for (int row = 0; row < 16; ++row) {
            f16x4 v = *(const f16x4*)(trans + row * 264 + lane * 4);
            *(f16x4*)(xwb + (size_t)(mrow0 + row) * 512 + half * 256 + lane * 4) = v;
        }
        __syncthreads();
    }
}

// ---------------------------------------------------------------------------
// K2: recurrence + fused FC. 16 WGs x 512 thr (8 waves, 2/SIMD).
// WG owns batches wg*4..wg*4+3. h lives in LDS replicated across 8 cols
// (col c holds batch c&3), so every lane works on valid data: zero
// predication in the hot loop. Wave w owns m-tiles 4w..4w+3.
// W_hh residency: kc 0..11 VGPR/AGPR (192 regs), kc 12..12+LKC-1 in LDS,
// remainder (LKC<4 fallback) prefetched from L2 per step.
// Two 8-deep MFMA chains per tile (accA: kc 0-7, accB: kc 8-15).
// ---------------------------------------------------------------------------
template<int LKC>
__global__ __launch_bounds__(512, 2) void k2_rnn(const f16* __restrict__ awhh,
                                                 const f16* __restrict__ xwb,
                                                 const float* __restrict__ Wfc,
                                                 const float* __restrict__ bfc,
                                                 float* __restrict__ out) {
    constexpr int SKC = 4 - LKC;                 // streamed kc count (kc 12+LKC..15)
    extern __shared__ char smem[];
    f16* fragS = (f16*)smem;                               // 32768*LKC B
    f16* hbuf  = (f16*)(smem + (size_t)32768 * LKC);       // 2*8*HSTRIDE f16

    int tid  = threadIdx.x;
    int wave = tid >> 6, lane = tid & 63;
    int quad = lane >> 4, n = lane & 15;
    int c    = n & 7;                // h column this lane reads/writes
    int mtb  = wave * 4;

    // --- persistent A-frags, kc 0..11 ---
    f16x8 areg[4][12];
#pragma unroll
    for (int p = 0; p < 4; ++p)
#pragma unroll
        for (int kc = 0; kc < 12; ++kc)
            areg[p][kc] = *(const f16x8*)(awhh +
                ((size_t)(kc * 32 + mtb + p) * 64 + lane) * 8);

    // --- LDS-resident frags, kc 12..12+LKC-1 (per-wave private region) ---
#pragma unroll
    for (int p = 0; p < 4; ++p)
#pragma unroll
        for (int j = 0; j < LKC; ++j) {
            f16x8 v = *(const f16x8*)(awhh +
                ((size_t)((12 + j) * 32 + mtb + p) * 64 + lane) * 8);
            *(f16x8*)(fragS + (((mtb + p) * LKC + j) * 64 + lane) * 8) = v;
        }

    // --- zero h double-buffer (2*8*HSTRIDE f16 = 4416 dwords) ---
    {
        unsigned int* hz = (unsigned int*)hbuf;
        for (int i = tid; i < 2 * 8 * HSTRIDE / 2; i += 512) hz[i] = 0u;
    }
    __syncthreads();

    // running xwb pointer for this lane's batch (n&3) and tile rows
    const f16* xptr = xwb + ((size_t)(blockIdx.x * 4 + (n & 3)) * 256) * 512
                          + quad * 4;

    for (int t = 0; t < 256; ++t) {
        const f16* hc = hbuf + (size_t)(t & 1) * 8 * HSTRIDE;
        f16*       hn = hbuf + (size_t)((t + 1) & 1) * 8 * HSTRIDE;

        // prefetch xw (h-independent; latency hidden by MFMA phase)
        f16x4 xw4[4];
#pragma unroll
        for (int p = 0; p < 4; ++p)
            xw4[p] = *(const f16x4*)(xptr + (mtb + p) * 16);
        xptr += 512;

        // streamed A-frags (fallback only; LKC=4 -> none)
        f16x8 sst[SKC > 0 ? SKC : 1][4];
        if (SKC > 0) {
#pragma unroll
            for (int q = 0; q < SKC; ++q)
#pragma unroll
                for (int p = 0; p < 4; ++p)
                    sst[q][p] = *(const f16x8*)(awhh +
                        ((size_t)((12 + LKC + q) * 32 + mtb + p) * 64 + lane) * 8);
        }

        f32x4 accA[4], accB[4];
#pragma unroll
        for (int p = 0; p < 4; ++p) {
            accA[p] = (f32x4){0.f, 0.f, 0.f, 0.f};
            accB[p] = (f32x4){0.f, 0.f, 0.f, 0.f};
        }

        // kc 0..7 -> accA (8-deep chain), all-register A
#pragma unroll
        for (int kc = 0; kc < 8; ++kc) {
            f16x8 bf = *(const f16x8*)(hc + c * HSTRIDE + kc * 32 + quad * 8);
#pragma unroll
            for (int p = 0; p < 4; ++p)
                accA[p] = __builtin_amdgcn_mfma_f32_16x16x32_f16(
                    areg[p][kc], bf, accA[p], 0, 0, 0);
        }
        // kc 8..11 -> accB, register A
#pragma unroll
        for (int kc = 8; kc < 12; ++kc) {
            f16x8 bf = *(const f16x8*)(hc + c * HSTRIDE + kc * 32 + quad * 8);
#pragma unroll
            for (int p = 0; p < 4; ++p)
                accB[p] = __builtin_amdgcn_mfma_f32_16x16x32_f16(
                    areg[p][kc], bf, accB[p], 0, 0, 0);
        }
        // kc 12..12+LKC-1 -> accB, LDS A
#pragma unroll
        for (int j = 0; j < LKC; ++j) {
            int kc = 12 + j;
            f16x8 bf = *(const f16x8*)(hc + c * HSTRIDE + kc * 32 + quad * 8);
#pragma unroll
            for (int p = 0; p < 4; ++p) {
                f16x8 af = *(const f16x8*)(fragS +
                    (((mtb + p) * LKC + j) * 64 + lane) * 8);
                accB[p] = __builtin_amdgcn_mfma_f32_16x16x32_f16(
                    af, bf, accB[p], 0, 0, 0);
            }
        }
        // streamed tail (fallback only)
        if (SKC > 0) {
#pragma unroll
            for (int q = 0; q < SKC; ++q) {
                int kc = 12 + LKC + q;
                f16x8 bf = *(const f16x8*)(hc + c * HSTRIDE + kc * 32 + quad * 8);
#pragma unroll
                for (int p = 0; p < 4; ++p)
                    accB[p] = __builtin_amdgcn_mfma_f32_16x16x32_f16(
                        sst[q][p], bf, accB[p], 0, 0, 0);
            }
        }

        // epilogue: all lanes uniform; tanh via exp + rcp
#pragma unroll
        for (int p = 0; p < 4; ++p) {
            int i0 = (mtb + p) * 16 + quad * 4;
            f16x4 hv;
#pragma unroll
            for (int r = 0; r < 4; ++r) {
                float z = accA[p][r] + accB[p][r] + (float)xw4[p][r];
                float e = __expf(2.f * z);       // bounded: |z| small
                hv[r] = (f16)((e - 1.f) * __builtin_amdgcn_rcpf(e + 1.f));
            }
            if (n < 8)
                *(f16x4*)(hn + c * HSTRIDE + i0) = hv;
        }
        __syncthreads();   // h(t+1) fully written before next step reads it
    }

    // ---- fused FC: h_T is in hbuf buffer 0, cols 0..3. fragS is dead.
    float* red = (float*)smem;           // 512 floats
    {
        int bb = tid >> 7;               // 0..3
        int oo = (tid >> 5) & 3;         // 0..3
        int sg = tid & 31;               // 0..31 -> 16 i each
        const f16* hrow = hbuf + bb * HSTRIDE;
        const float* wrow = Wfc + (size_t)oo * 512;
        float s = 0.f;
#pragma unroll
        for (int ii = 0; ii < 16; ++ii) {
            int i = sg * 16 + ii;
            s += (float)hrow[i] * wrow[i];
        }
        __syncthreads();                 // fragS reads all done before overwrite
        red[tid] = s;
    }
    __syncthreads();
    if (tid < 16) {
        int bb = tid >> 2, oo = tid & 3;
        float s = 0.f;
#pragma unroll
        for (int sg = 0; sg < 32; ++sg) s += red[(bb * 4 + oo) * 32 + sg];
        out[(blockIdx.x * 4 + bb) * 4 + oo] = s + bfc[oo];
    }
}

extern "C" void kernel_launch(void* const* d_in, const int* in_sizes, int n_in,
                              void* d_out, int out_size, void* d_ws, size_t ws_size,
                              hipStream_t stream) {
    const int*   x   = (const int*)d_in[0];
    const float* emb = (const float*)d_in[1];
    const float* Wih = (const float*)d_in[2];
    const float* Whh = (const float*)d_in[3];
    const float* bih = (const float*)d_in[4];
    const float* bhh = (const float*)d_in[5];
    const float* Wfc = (const float*)d_in[6];
    const float* bfc = (const float*)d_in[7];
    float* out = (float*)d_out;

    char* ws = (char*)d_ws;
    f16* xwb  = (f16*)(ws + XWB_OFF);
    f16* awhh = (f16*)(ws + AWHH_OFF);
    f16* bwih = (f16*)(ws + BWIH_OFF);

    hipLaunchKernelGGL(k0_prep, dim3(1024), dim3(64),  0, stream, Whh, Wih, awhh, bwih);
    hipLaunchKernelGGL(k1_xw,   dim3(256),  dim3(256), 0, stream, x, emb, bih, bhh, bwih, xwb);

    const int HB = 2 * 8 * HSTRIDE * 2;       // 17664 B
    const int LDS_BIG   = 32768 * 4 + HB;     // 148736
    const int LDS_SMALL = 32768 * 1 + HB;     // 50432
    int dev = 0;
    (void)hipGetDevice(&dev);
    int maxlds = 0;
    (void)hipDeviceGetAttribute(&maxlds, hipDeviceAttributeMaxSharedMemoryPerBlock, dev);
    bool big = maxlds >= LDS_BIG;
    if (big)
        big = (hipFuncSetAttribute((const void*)&k2_rnn<4>,
                                   hipFuncAttributeMaxDynamicSharedMemorySize,
                                   LDS_BIG) == hipSuccess);
    if (big) {
        hipLaunchKernelGGL(k2_rnn<4>, dim3(16), dim3(512), LDS_BIG, stream,
                           awhh, xwb, Wfc, bfc, out);
    } else {
        (void)hipFuncSetAttribute((const void*)&k2_rnn<1>,
                                  hipFuncAttributeMaxDynamicSharedMemorySize,
                                  LDS_SMALL);
        hipLaunchKernelGGL(k2_rnn<1>, dim3(16), dim3(512), LDS_SMALL, stream,
                           awhh, xwb, Wfc, bfc, out);
    }
}

// Round 6
// 708.839 us; speedup vs baseline: 1.2106x; 1.0305x over previous
//
#include <hip/hip_runtime.h>
#include <hip/hip_bf16.h>

// RNN: emb[x] -> xw GEMM -> 256 sequential tanh steps -> fused FC.
// All matmuls in f16 MFMA (16x16x32) with f32 accumulate.
// B=64, T=256, H=E=512, O=4.
//
// R6: h stored in 4 LDS columns, stride 528 f16 (264 dwords = 8 mod 32).
// bf read col = n&3: 4-lane broadcast + exact 2-way bank spread = free.
// LDS pipe/step drops ~3600 -> ~2300 cyc, below the 2483-cyc MFMA issue
// floor. Rest is R5: areg 12 kc + fragS 4 kc, dual 8-deep MFMA chains,
// rcp-tanh, running xwb pointer, fused FC.

typedef _Float16 f16;
typedef _Float16 f16x4 __attribute__((ext_vector_type(4)));
typedef _Float16 f16x8 __attribute__((ext_vector_type(8)));
typedef float    f32x4 __attribute__((ext_vector_type(4)));

// d_ws layout (bytes)
#define XWB_OFF   0u
#define XWB_BYTES (64u*256u*512u*2u)            // 16 MB: xw + b_ih + b_hh, f16 [B*T][H]
#define AWHH_OFF  (XWB_OFF + XWB_BYTES)         // 512 KB: W_hh A-operand fragments
#define BWIH_OFF  (AWHH_OFF + 512u*1024u)       // 512 KB: W_ih B-operand fragments

#define HSTRIDE 528     // f16 col stride: 264 dwords = 8 mod 32 -> 2-way spread

// ---------------------------------------------------------------------------
// K0: pack W_hh (A-op layout) and W_ih (B-op layout) into fragment-linear
// f16: frag (kc, tile) at ((kc*32 + tile)*64 + lane)*8 f16.
// ---------------------------------------------------------------------------
__global__ __launch_bounds__(64) void k0_prep(const float* __restrict__ Whh,
                                              const float* __restrict__ Wih,
                                              f16* __restrict__ awhh,
                                              f16* __restrict__ bwih) {
    int id   = blockIdx.x;           // 0..1023
    int lane = threadIdx.x;          // 0..63
    bool is_ih = id >= 512;
    int lid = is_ih ? (id - 512) : id;       // = kc*32 + tile
    const float* src = is_ih ? Wih : Whh;
    f16* dst = is_ih ? bwih : awhh;
    int tile = lid & 31;
    int kc   = lid >> 5;
    int row  = tile * 16 + (lane & 15);
    int col0 = kc * 32 + (lane >> 4) * 8;
    const float* p = src + (size_t)row * 512 + col0;
    float4 v0 = *(const float4*)(p);
    float4 v1 = *(const float4*)(p + 4);
    f16x8 o;
    o[0] = (f16)v0.x; o[1] = (f16)v0.y; o[2] = (f16)v0.z; o[3] = (f16)v0.w;
    o[4] = (f16)v1.x; o[5] = (f16)v1.y; o[6] = (f16)v1.z; o[7] = (f16)v1.w;
    *(f16x8*)(dst + (size_t)lid * 512 + lane * 8) = o;
}

// ---------------------------------------------------------------------------
// K1: xwb[m][n] = sum_k emb[x[m]][k] * W_ih[n][k] + b_ih[n] + b_hh[n], f16.
// Double-buffered LDS staging (1 barrier/iter); LDS-transpose epilogue for
// coalesced 8 B/lane stores.
// ---------------------------------------------------------------------------
__global__ __launch_bounds__(256) void k1_xw(const int* __restrict__ x,
                                             const float* __restrict__ emb,
                                             const float* __restrict__ bih,
                                             const float* __restrict__ bhh,
                                             const f16* __restrict__ bwih,
                                             f16* __restrict__ xwb) {
    __shared__ f16 Bs[2][16384];     // 64 KB: double-buffered k-chunk of B frags
    int tid  = threadIdx.x;
    int wave = tid >> 6, lane = tid & 63;
    int quad = lane >> 4, l15 = lane & 15;
    int mrow0 = blockIdx.x * 64 + wave * 16;

    int arow_idx = x[mrow0 + l15];                  // gathered embedding row
    const float* arow = emb + (size_t)arow_idx * 512;

    f32x4 acc[32];
#pragma unroll
    for (int nt = 0; nt < 32; ++nt) acc[nt] = (f32x4){0.f, 0.f, 0.f, 0.f};

    // prologue: stage kc=0, preload kc=1 into regs
    float4 L[8];
    {
        const float4* s4 = (const float4*)bwih;
#pragma unroll
        for (int q = 0; q < 8; ++q) L[q] = s4[q * 256 + tid];
#pragma unroll
        for (int q = 0; q < 8; ++q) ((float4*)Bs[0])[q * 256 + tid] = L[q];
        const float4* s4b = (const float4*)(bwih + 16384);
#pragma unroll
        for (int q = 0; q < 8; ++q) L[q] = s4b[q * 256 + tid];
    }
    __syncthreads();

    for (int kc = 0; kc < 16; ++kc) {
        int cur = kc & 1;

        float4 a0 = *(const float4*)(arow + kc * 32 + quad * 8);
        float4 a1 = *(const float4*)(arow + kc * 32 + quad * 8 + 4);
        f16x8 af;
        af[0] = (f16)a0.x; af[1] = (f16)a0.y; af[2] = (f16)a0.z; af[3] = (f16)a0.w;
        af[4] = (f16)a1.x; af[5] = (f16)a1.y; af[6] = (f16)a1.z; af[7] = (f16)a1.w;

#pragma unroll
        for (int nt = 0; nt < 32; ++nt) {
            f16x8 bf = *(const f16x8*)(&Bs[cur][0] + nt * 512 + lane * 8);
            acc[nt] = __builtin_amdgcn_mfma_f32_16x16x32_f16(af, bf, acc[nt], 0, 0, 0);
        }

        if (kc < 15) {   // store prefetched (kc+1) into the other buffer
#pragma unroll
            for (int q = 0; q < 8; ++q) ((float4*)Bs[cur ^ 1])[q * 256 + tid] = L[q];
        }
        __syncthreads();
        if (kc < 14) {   // issue loads for kc+2; drain covered by next MFMAs
            const float4* s4 = (const float4*)(bwih + (size_t)(kc + 2) * 16384);
#pragma unroll
            for (int q = 0; q < 8; ++q) L[q] = s4[q * 256 + tid];
        }
    }
    __syncthreads();   // Bs reads done everywhere; safe to reuse as scratch

    // Epilogue: transpose via per-wave LDS region, then coalesced stores.
    f16* trans = (f16*)Bs + (size_t)wave * 4224;
#pragma unroll
    for (int half = 0; half < 2; ++half) {
#pragma unroll
        for (int nt2 = 0; nt2 < 16; ++nt2) {
            int nt = half * 16 + nt2;
            int n = nt * 16 + l15;
            float bias = bih[n] + bhh[n];
#pragma unroll
            for (int r = 0; r < 4; ++r)
                trans[(quad * 4 + r) * 264 + nt2 * 16 + l15] =
                    (f16)(acc[nt][r] + bias);
        }
#pragma unroll
        for (int row = 0; row < 16; ++row) {
            f16x4 v = *(const f16x4*)(trans + row * 264 + lane * 4);
            *(f16x4*)(xwb + (size_t)(mrow0 + row) * 512 + half * 256 + lane * 4) = v;
        }
        __syncthreads();
    }
}

// ---------------------------------------------------------------------------
// K2: recurrence + fused FC. 16 WGs x 512 thr (8 waves, 2/SIMD).
// WG owns batches wg*4..wg*4+3. h in LDS: 4 cols, stride 528 f16.
// bf read col = n&3 -> 4-lane broadcast + 2-way bank spread (both free).
// Wave w owns m-tiles 4w..4w+3. W_hh: kc 0..11 in regs (unified VGPR/AGPR),
// kc 12..12+LKC-1 in LDS fragS, remainder streamed (LKC=4 -> none).
// Two 8-deep MFMA chains per tile. Epilogue: +xwb, rcp-tanh; n<4 writes h.
// ---------------------------------------------------------------------------
template<int LKC>
__global__ __launch_bounds__(512, 2) void k2_rnn(const f16* __restrict__ awhh,
                                                 const f16* __restrict__ xwb,
                                                 const float* __restrict__ Wfc,
                                                 const float* __restrict__ bfc,
                                                 float* __restrict__ out) {
    constexpr int SKC = 4 - LKC;                 // streamed kc count (kc 12+LKC..15)
    extern __shared__ char smem[];
    f16* fragS = (f16*)smem;                               // 32768*LKC B
    f16* hbuf  = (f16*)(smem + (size_t)32768 * LKC);       // 2*4*HSTRIDE f16 = 8448 B

    int tid  = threadIdx.x;
    int wave = tid >> 6, lane = tid & 63;
    int quad = lane >> 4, n = lane & 15;
    int c    = n & 3;                // h column this lane reads (broadcast x4)
    int mtb  = wave * 4;

    // --- persistent A-frags, kc 0..11 ---
    f16x8 areg[4][12];
#pragma unroll
    for (int p = 0; p < 4; ++p)
#pragma unroll
        for (int kc = 0; kc < 12; ++kc)
            areg[p][kc] = *(const f16x8*)(awhh +
                ((size_t)(kc * 32 + mtb + p) * 64 + lane) * 8);

    // --- LDS-resident frags, kc 12..12+LKC-1 (per-wave private region) ---
#pragma unroll
    for (int p = 0; p < 4; ++p)
#pragma unroll
        for (int j = 0; j < LKC; ++j) {
            f16x8 v = *(const f16x8*)(awhh +
                ((size_t)((12 + j) * 32 + mtb + p) * 64 + lane) * 8);
            *(f16x8*)(fragS + (((mtb + p) * LKC + j) * 64 + lane) * 8) = v;
        }

    // --- zero h double-buffer (2*4*HSTRIDE f16 = 2112 dwords) ---
    {
        unsigned int* hz = (unsigned int*)hbuf;
        for (int i = tid; i < 2 * 4 * HSTRIDE / 2; i += 512) hz[i] = 0u;
    }
    __syncthreads();

    // running xwb pointer for this lane's batch (n&3) and tile rows
    const f16* xptr = xwb + ((size_t)(blockIdx.x * 4 + c) * 256) * 512
                          + quad * 4;

    for (int t = 0; t < 256; ++t) {
        const f16* hc = hbuf + (size_t)(t & 1) * 4 * HSTRIDE;
        f16*       hn = hbuf + (size_t)((t + 1) & 1) * 4 * HSTRIDE;

        // prefetch xw (h-independent; latency hidden by MFMA phase)
        f16x4 xw4[4];
#pragma unroll
        for (int p = 0; p < 4; ++p)
            xw4[p] = *(const f16x4*)(xptr + (mtb + p) * 16);
        xptr += 512;

        // streamed A-frags (fallback only; LKC=4 -> none)
        f16x8 sst[SKC > 0 ? SKC : 1][4];
        if (SKC > 0) {
#pragma unroll
            for (int q = 0; q < SKC; ++q)
#pragma unroll
                for (int p = 0; p < 4; ++p)
                    sst[q][p] = *(const f16x8*)(awhh +
                        ((size_t)((12 + LKC + q) * 32 + mtb + p) * 64 + lane) * 8);
        }

        f32x4 accA[4], accB[4];
#pragma unroll
        for (int p = 0; p < 4; ++p) {
            accA[p] = (f32x4){0.f, 0.f, 0.f, 0.f};
            accB[p] = (f32x4){0.f, 0.f, 0.f, 0.f};
        }

        // kc 0..7 -> accA (8-deep chain), all-register A
#pragma unroll
        for (int kc = 0; kc < 8; ++kc) {
            f16x8 bf = *(const f16x8*)(hc + c * HSTRIDE + kc * 32 + quad * 8);
#pragma unroll
            for (int p = 0; p < 4; ++p)
                accA[p] = __builtin_amdgcn_mfma_f32_16x16x32_f16(
                    areg[p][kc], bf, accA[p], 0, 0, 0);
        }
        // kc 8..11 -> accB, register A
#pragma unroll
        for (int kc = 8; kc < 12; ++kc) {
            f16x8 bf = *(const f16x8*)(hc + c * HSTRIDE + kc * 32 + quad * 8);
#pragma unroll
            for (int p = 0; p < 4; ++p)
                accB[p] = __builtin_amdgcn_mfma_f32_16x16x32_f16(
                    areg[p][kc], bf, accB[p], 0, 0, 0);
        }
        // kc 12..12+LKC-1 -> accB, LDS A
#pragma unroll
        for (int j = 0; j < LKC; ++j) {
            int kc = 12 + j;
            f16x8 bf = *(const f16x8*)(hc + c * HSTRIDE + kc * 32 + quad * 8);
#pragma unroll
            for (int p = 0; p < 4; ++p) {
                f16x8 af = *(const f16x8*)(fragS +
                    (((mtb + p) * LKC + j) * 64 + lane) * 8);
                accB[p] = __builtin_amdgcn_mfma_f32_16x16x32_f16(
                    af, bf, accB[p], 0, 0, 0);
            }
        }
        // streamed tail (fallback only)
        if (SKC > 0) {
#pragma unroll
            for (int q = 0; q < SKC; ++q) {
                int kc = 12 + LKC + q;
                f16x8 bf = *(const f16x8*)(hc + c * HSTRIDE + kc * 32 + quad * 8);
#pragma unroll
                for (int p = 0; p < 4; ++p)
                    accB[p] = __builtin_amdgcn_mfma_f32_16x16x32_f16(
                        sst[q][p], bf, accB[p], 0, 0, 0);
            }
        }

        // epilogue: all lanes compute (uniform); only n<4 write (b64,
        // 16 lanes -> 32 distinct banks, conflict-free)
#pragma unroll
        for (int p = 0; p < 4; ++p) {
            int i0 = (mtb + p) * 16 + quad * 4;
            f16x4 hv;
#pragma unroll
            for (int r = 0; r < 4; ++r) {
                float z = accA[p][r] + accB[p][r] + (float)xw4[p][r];
                float e = __expf(2.f * z);       // bounded: |z| small
                hv[r] = (f16)((e - 1.f) * __builtin_amdgcn_rcpf(e + 1.f));
            }
            if (n < 4)
                *(f16x4*)(hn + c * HSTRIDE + i0) = hv;
        }
        __syncthreads();   // h(t+1) fully written before next step reads it
    }

    // ---- fused FC: h_T is in hbuf buffer 0, cols 0..3. fragS is dead.
    float* red = (float*)smem;           // 512 floats
    {
        int bb = tid >> 7;               // 0..3
        int oo = (tid >> 5) & 3;         // 0..3
        int sg = tid & 31;               // 0..31 -> 16 i each
        const f16* hrow = hbuf + bb * HSTRIDE;
        const float* wrow = Wfc + (size_t)oo * 512;
        float s = 0.f;
#pragma unroll
        for (int ii = 0; ii < 16; ++ii) {
            int i = sg * 16 + ii;
            s += (float)hrow[i] * wrow[i];
        }
        __syncthreads();                 // fragS reads all done before overwrite
        red[tid] = s;
    }
    __syncthreads();
    if (tid < 16) {
        int bb = tid >> 2, oo = tid & 3;
        float s = 0.f;
#pragma unroll
        for (int sg = 0; sg < 32; ++sg) s += red[(bb * 4 + oo) * 32 + sg];
        out[(blockIdx.x * 4 + bb) * 4 + oo] = s + bfc[oo];
    }
}

extern "C" void kernel_launch(void* const* d_in, const int* in_sizes, int n_in,
                              void* d_out, int out_size, void* d_ws, size_t ws_size,
                              hipStream_t stream) {
    const int*   x   = (const int*)d_in[0];
    const float* emb = (const float*)d_in[1];
    const float* Wih = (const float*)d_in[2];
    const float* Whh = (const float*)d_in[3];
    const float* bih = (const float*)d_in[4];
    const float* bhh = (const float*)d_in[5];
    const float* Wfc = (const float*)d_in[6];
    const float* bfc = (const float*)d_in[7];
    float* out = (float*)d_out;

    char* ws = (char*)d_ws;
    f16* xwb  = (f16*)(ws + XWB_OFF);
    f16* awhh = (f16*)(ws + AWHH_OFF);
    f16* bwih = (f16*)(ws + BWIH_OFF);

    hipLaunchKernelGGL(k0_prep, dim3(1024), dim3(64),  0, stream, Whh, Wih, awhh, bwih);
    hipLaunchKernelGGL(k1_xw,   dim3(256),  dim3(256), 0, stream, x, emb, bih, bhh, bwih, xwb);

    const int HB = 2 * 4 * HSTRIDE * 2;       // 8448 B
    const int LDS_BIG   = 32768 * 4 + HB;     // 139520
    const int LDS_SMALL = 32768 * 1 + HB;     // 41216
    int dev = 0;
    (void)hipGetDevice(&dev);
    int maxlds = 0;
    (void)hipDeviceGetAttribute(&maxlds, hipDeviceAttributeMaxSharedMemoryPerBlock, dev);
    bool big = maxlds >= LDS_BIG;
    if (big)
        big = (hipFuncSetAttribute((const void*)&k2_rnn<4>,
                                   hipFuncAttributeMaxDynamicSharedMemorySize,
                                   LDS_BIG) == hipSuccess);
    if (big) {
        hipLaunchKernelGGL(k2_rnn<4>, dim3(16), dim3(512), LDS_BIG, stream,
                           awhh, xwb, Wfc, bfc, out);
    } else {
        (void)hipFuncSetAttribute((const void*)&k2_rnn<1>,
                                  hipFuncAttributeMaxDynamicSharedMemorySize,
                                  LDS_SMALL);
        hipLaunchKernelGGL(k2_rnn<1>, dim3(16), dim3(512), LDS_SMALL, stream,
                           awhh, xwb, Wfc, bfc, out);
    }
}